// Round 8
// baseline (1419.116 us; speedup 1.0000x reference)
//
#include <hip/hip_runtime.h>
#include <stdint.h>

// SmallMLP_INR: fused 6-layer MLP (2->256->256x4->1, ReLU) over 524288 points.
// Split-bf16 MFMA (x = hi + lo, truncate split): Y = Xh*Wh + Xh*Wl + Xl*Wh in fp32.
// Operand-swapped: Yt = Wt * Xt (weights = A-frag from global, acts = B-frag in LDS).
// R8: MT=48 -> LDS 48 KB -> 3 blocks/CU -> 6 waves/SIMD (was 2 blocks / 4 waves).
// Model (calibrated R6/R7): MFMA busy time is pinned at the 397 us split-MFMA
// floor; idle fraction = serial phases not covered by co-resident blocks.
// R7: 2 blocks/CU -> util 70%. 3 blocks/CU -> 2 peers cover each block's serial
// phases -> predicted util ~78%. L2 weight traffic 11.4 GB (~23 TB/s, 67% of
// ceiling -- safe; R3's failure was at ~43 TB/s). Tail block (32 pts): coords
// clamped, out guarded. Everything else identical to R7.

#define WIDTH 256
#define MT 48

typedef short short8 __attribute__((ext_vector_type(8)));
typedef float float4v __attribute__((ext_vector_type(4)));
typedef unsigned int uint2v __attribute__((ext_vector_type(2)));

// truncate-split f32 -> bf16 hi + bf16 lo (lo also truncated; total ~16-17 bits)
__device__ __forceinline__ void split_bf(float f, unsigned short &hi, unsigned short &lo) {
    union { float f; uint32_t u; } a; a.f = f;
    hi = (unsigned short)(a.u >> 16);
    union { uint32_t u; float f; } h; h.u = a.u & 0xffff0000u;
    union { float f; uint32_t u; } d; d.f = f - h.f;   // exact (Sterbenz)
    lo = (unsigned short)(d.u >> 16);
}

// pack hi(bf16) of two f32 into one u32 via v_perm_b32: D = {a.b2,a.b3,b.b2,b.b3}
__device__ __forceinline__ uint32_t phi2(float a, float b) {
    return __builtin_amdgcn_perm(__float_as_uint(b), __float_as_uint(a), 0x07060302u);
}
// pack lo(bf16) of two f32: residual after hi-truncation, then perm-pack
__device__ __forceinline__ uint32_t plo2(float a, float b) {
    float da = a - __uint_as_float(__float_as_uint(a) & 0xffff0000u);
    float db = b - __uint_as_float(__float_as_uint(b) & 0xffff0000u);
    return __builtin_amdgcn_perm(__float_as_uint(db), __float_as_uint(da), 0x07060302u);
}

// LDS activation addressing: X[m][n], row stride 256 ushorts, 16B-chunk index
// XOR-swizzled by (m&7) -> bank-minimal MFMA B-frag reads without padding.
__device__ __forceinline__ int xaddr(int m, int n) {
    int c = n >> 3;
    return m * 256 + (((c ^ (m & 7)) << 3) | (n & 7));
}

// Pack W2..W5 (256x256, row-major [k][n]) into MFMA fragment order:
// [l][ct(16)][ks(8)][lane(64)][j(8)], n = 16*ct + (lane&15), k = 32*ks + 8*(lane>>4) + j.
__global__ void prep_weights(const float* __restrict__ W2, const float* __restrict__ W3,
                             const float* __restrict__ W4, const float* __restrict__ W5,
                             unsigned short* __restrict__ whi, unsigned short* __restrict__ wlo) {
    int tid = blockIdx.x * 256 + threadIdx.x;   // 4*65536 total
    int l = tid >> 16;
    int e = tid & 65535;
    int j = e & 7;
    int lane = (e >> 3) & 63;
    int ks = (e >> 9) & 7;
    int ct = (e >> 12) & 15;
    int n = ct * 16 + (lane & 15);
    int k = ks * 32 + (lane >> 4) * 8 + j;
    const float* W = (l == 0) ? W2 : (l == 1) ? W3 : (l == 2) ? W4 : W5;
    float w = W[k * 256 + n];
    unsigned short hi, lo;
    split_bf(w, hi, lo);
    whi[tid] = hi;
    wlo[tid] = lo;
}

// weight A-frag load: ct = 2*wv + ft (wave owns 32 consecutive features)
#define LOADW(WH, WL, L, KS)                                                   \
    do {                                                                       \
        _Pragma("unroll")                                                      \
        for (int _ft = 0; _ft < 2; ++_ft) {                                    \
            const int _idx = ((((L) * 16) + (2 * wv + _ft)) * 8 + (KS)) * 512  \
                             + lane * 8;                                       \
            WH[_ft] = *(const short8*)(whi + _idx);                            \
            WL[_ft] = *(const short8*)(wlo + _idx);                            \
        }                                                                      \
    } while (0)

__global__ __launch_bounds__(512, 6) void mlp_fused(
    const float* __restrict__ coords,
    const float* __restrict__ W1, const float* __restrict__ b1,
    const float* __restrict__ b2, const float* __restrict__ b3,
    const float* __restrict__ b4, const float* __restrict__ b5,
    const float* __restrict__ W6, const float* __restrict__ b6,
    const unsigned short* __restrict__ whi, const unsigned short* __restrict__ wlo,
    float* __restrict__ out, int N)
{
    __shared__ unsigned short Xhi[MT * 256];   // 24 KB
    __shared__ unsigned short Xlo[MT * 256];   // 24 KB  (total 48 KB -> 3 blocks/CU)

    const int tid = threadIdx.x;
    const int m0 = blockIdx.x * MT;

    const int wv   = tid >> 6;     // wave 0..7 owns output features [32*wv, 32*wv+32)
    const int lane = tid & 63;
    const int quad = lane >> 4;
    const int l16  = lane & 15;

    // issue first weight loads NOW -- L2 latency hides under layer 1 + barrier
    short8 cwh[2], cwl[2];
    LOADW(cwh, cwl, 0, 0);

    // ---- layer 1: 2 -> 256 (VALU) -> X. Thread owns 4 cols, 6 rounds. ----
    {
        const int nq = lane * 4;
        const float4v w0 = *(const float4v*)(W1 + nq);          // W1[0][nq..nq+3]
        const float4v w1 = *(const float4v*)(W1 + WIDTH + nq);  // W1[1][nq..nq+3]
        const float4v bb = *(const float4v*)(b1 + nq);
        #pragma unroll
        for (int i = 0; i < MT / 8; ++i) {
            const int m = 8 * i + wv;
            int mg = m0 + m;                  // clamp tail block (dup data, finite)
            if (mg >= N) mg = N - 1;
            const float c0 = coords[mg * 2];  // wave-uniform address
            const float c1 = coords[mg * 2 + 1];
            float v[4];
            #pragma unroll
            for (int j = 0; j < 4; ++j)
                v[j] = fmaxf(fmaf(c0, w0[j], fmaf(c1, w1[j], bb[j])), 0.0f);
            const int a = xaddr(m, nq);       // nq&7 in {0,4}: stays in chunk
            *(uint2v*)(Xhi + a) = (uint2v){phi2(v[0], v[1]), phi2(v[2], v[3])};
            *(uint2v*)(Xlo + a) = (uint2v){plo2(v[0], v[1]), plo2(v[2], v[3])};
        }
    }
    __syncthreads();

    float sdot[3] = {0.f, 0.f, 0.f};   // fused layer-6 partials

    // ---- layers 2..5: 256 -> 256 via 16x16x32 bf16 MFMA, operand-swapped.
    //      Single X buffer: barrier after reads, barrier after writes. ----
    #pragma unroll
    for (int l = 0; l < 4; ++l) {
        const float* bias = (l == 0) ? b2 : (l == 1) ? b3 : (l == 2) ? b4 : b5;

        float4v acc[2][3];   // acc[ft][pt] -- 24 VGPRs
        #pragma unroll
        for (int ft = 0; ft < 2; ++ft)
            #pragma unroll
            for (int pt = 0; pt < 3; ++pt)
                acc[ft][pt] = (float4v){0.f, 0.f, 0.f, 0.f};

        #pragma unroll
        for (int ks = 0; ks < 8; ++ks) {
            // prefetch next weights (next ks, or next layer's ks=0)
            short8 nwh[2], nwl[2];
            if (ks < 7) {
                LOADW(nwh, nwl, l, ks + 1);
            } else if (l < 3) {
                LOADW(nwh, nwl, l + 1, 0);
            }
            // B-frags just-in-time from LDS: B[k][p], p = l16, k = 32*ks+8*quad+j
            short8 xh[3], xl[3];
            #pragma unroll
            for (int pt = 0; pt < 3; ++pt) {
                const int off = xaddr(16 * pt + l16, 32 * ks + 8 * quad);
                xh[pt] = *(const short8*)(Xhi + off);
                xl[pt] = *(const short8*)(Xlo + off);
            }
            __builtin_amdgcn_s_setprio(1);
            // product-major: dependent same-acc MFMAs 6 issue slots apart
            #pragma unroll
            for (int ft = 0; ft < 2; ++ft)
                #pragma unroll
                for (int pt = 0; pt < 3; ++pt)
                    acc[ft][pt] = __builtin_amdgcn_mfma_f32_16x16x32_bf16(cwh[ft], xh[pt], acc[ft][pt], 0, 0, 0);
            #pragma unroll
            for (int ft = 0; ft < 2; ++ft)
                #pragma unroll
                for (int pt = 0; pt < 3; ++pt)
                    acc[ft][pt] = __builtin_amdgcn_mfma_f32_16x16x32_bf16(cwh[ft], xl[pt], acc[ft][pt], 0, 0, 0);
            #pragma unroll
            for (int ft = 0; ft < 2; ++ft)
                #pragma unroll
                for (int pt = 0; pt < 3; ++pt)
                    acc[ft][pt] = __builtin_amdgcn_mfma_f32_16x16x32_bf16(cwl[ft], xh[pt], acc[ft][pt], 0, 0, 0);
            __builtin_amdgcn_s_setprio(0);
            // rotate (SSA renames under full unroll -- no real moves)
            cwh[0] = nwh[0]; cwh[1] = nwh[1];
            cwl[0] = nwl[0]; cwl[1] = nwl[1];
        }
        __syncthreads();   // all waves done READING X before overwrite

        if (l < 3) {
            // epilogue: D row = 4*quad + r (4 consecutive features), col = point.
            // bias+ReLU+perm-pack, b64 writes back into X.
            #pragma unroll
            for (int ft = 0; ft < 2; ++ft) {
                const int nb = 32 * wv + 16 * ft + 4 * quad;   // nb&7 in {0,4}
                const float4v bb = *(const float4v*)(bias + nb);
                #pragma unroll
                for (int pt = 0; pt < 3; ++pt) {
                    const int m = 16 * pt + l16;
                    float v[4];
                    #pragma unroll
                    for (int r = 0; r < 4; ++r)
                        v[r] = fmaxf(acc[ft][pt][r] + bb[r], 0.0f);
                    const int a = xaddr(m, nb);
                    *(uint2v*)(Xhi + a) = (uint2v){phi2(v[0], v[1]), phi2(v[2], v[3])};
                    *(uint2v*)(Xlo + a) = (uint2v){plo2(v[0], v[1]), plo2(v[2], v[3])};
                }
            }
            __syncthreads();   // writes visible before next layer's reads
        } else {
            // fused layer 6: bias5 + ReLU + dot W6 straight from acc (full f32)
            #pragma unroll
            for (int ft = 0; ft < 2; ++ft) {
                const int nb = 32 * wv + 16 * ft + 4 * quad;
                const float4v bb = *(const float4v*)(bias + nb);   // b5
                const float4v w6 = *(const float4v*)(W6 + nb);
                #pragma unroll
                for (int pt = 0; pt < 3; ++pt)
                    #pragma unroll
                    for (int r = 0; r < 4; ++r) {
                        const float v = fmaxf(acc[ft][pt][r] + bb[r], 0.0f);
                        sdot[pt] = fmaf(v, w6[r], sdot[pt]);
                    }
            }
        }
    }

    // ---- layer-6 reduction: quad-shuffle, then cross-wave via LDS ----
    // (post-ks-loop barrier above guarantees all waves are done reading X)
    {
        float* part = (float*)Xhi;
        #pragma unroll
        for (int pt = 0; pt < 3; ++pt) {
            float s = sdot[pt];
            s += __shfl_xor(s, 16);
            s += __shfl_xor(s, 32);
            if (lane < 16) part[wv * 64 + pt * 16 + l16] = s;
        }
        __syncthreads();
        if (tid < MT && m0 + tid < N) {
            float s = b6[0];
            #pragma unroll
            for (int w = 0; w < 8; ++w)
                s += part[w * 64 + tid];
            out[m0 + tid] = s;
        }
    }
}

extern "C" void kernel_launch(void* const* d_in, const int* in_sizes, int n_in,
                              void* d_out, int out_size, void* d_ws, size_t ws_size,
                              hipStream_t stream) {
    const float* coords = (const float*)d_in[0];
    const float* W1 = (const float*)d_in[1];
    const float* b1 = (const float*)d_in[2];
    const float* W2 = (const float*)d_in[3];
    const float* b2 = (const float*)d_in[4];
    const float* W3 = (const float*)d_in[5];
    const float* b3 = (const float*)d_in[6];
    const float* W4 = (const float*)d_in[7];
    const float* b4 = (const float*)d_in[8];
    const float* W5 = (const float*)d_in[9];
    const float* b5 = (const float*)d_in[10];
    const float* W6 = (const float*)d_in[11];
    const float* b6 = (const float*)d_in[12];
    float* out = (float*)d_out;

    unsigned short* whi = (unsigned short*)d_ws;        // 4*65536 ushorts = 512 KB
    unsigned short* wlo = whi + 4 * 65536;              // 512 KB (ws total 1 MB)

    prep_weights<<<1024, 256, 0, stream>>>(W2, W3, W4, W5, whi, wlo);

    const int N = out_size;
    const int nblocks = (N + MT - 1) / MT;              // 524288 / 48 -> 10923
    mlp_fused<<<nblocks, 512, 0, stream>>>(coords, W1, b1, b2, b3, b4, b5,
                                           W6, b6, whi, wlo, out, N);
}

// Round 9
// 702.410 us; speedup vs baseline: 2.0204x; 2.0204x over previous
//
#include <hip/hip_runtime.h>
#include <stdint.h>

// SmallMLP_INR: fused 6-layer MLP (2->256->256x4->1, ReLU) over 524288 points.
// Split-bf16 MFMA (x = hi + lo, truncate split): Y = Xh*Wh + Xh*Wl + Xl*Wh in fp32.
// Operand-swapped: Yt = Wt * Xt (weights = A-frag from global, acts = B-frag in LDS).
// R9 = R8 with the launch_bounds bug fixed. R8's __launch_bounds__(512,6) capped
// the allocator at ~40 arch VGPRs -> scratch spills (FETCH 1.4 GB, WRITE 3.4 GB).
// (512,4) restores the 128-VGPR budget (R7 compiled to 60 VGPR, spill-free);
// hardware occupancy is still LDS-limited at 3 blocks/CU (48KB x 3 = 144 <= 160)
// = 6 waves/SIMD, which is the actual R8 hypothesis: 2 peer blocks cover each
// block's serial phases (layer1, epilogues, reduce, barriers).

#define WIDTH 256
#define MT 48

typedef short short8 __attribute__((ext_vector_type(8)));
typedef float float4v __attribute__((ext_vector_type(4)));
typedef unsigned int uint2v __attribute__((ext_vector_type(2)));

// truncate-split f32 -> bf16 hi + bf16 lo (lo also truncated; total ~16-17 bits)
__device__ __forceinline__ void split_bf(float f, unsigned short &hi, unsigned short &lo) {
    union { float f; uint32_t u; } a; a.f = f;
    hi = (unsigned short)(a.u >> 16);
    union { uint32_t u; float f; } h; h.u = a.u & 0xffff0000u;
    union { float f; uint32_t u; } d; d.f = f - h.f;   // exact (Sterbenz)
    lo = (unsigned short)(d.u >> 16);
}

// pack hi(bf16) of two f32 into one u32 via v_perm_b32: D = {a.b2,a.b3,b.b2,b.b3}
__device__ __forceinline__ uint32_t phi2(float a, float b) {
    return __builtin_amdgcn_perm(__float_as_uint(b), __float_as_uint(a), 0x07060302u);
}
// pack lo(bf16) of two f32: residual after hi-truncation, then perm-pack
__device__ __forceinline__ uint32_t plo2(float a, float b) {
    float da = a - __uint_as_float(__float_as_uint(a) & 0xffff0000u);
    float db = b - __uint_as_float(__float_as_uint(b) & 0xffff0000u);
    return __builtin_amdgcn_perm(__float_as_uint(db), __float_as_uint(da), 0x07060302u);
}

// LDS activation addressing: X[m][n], row stride 256 ushorts, 16B-chunk index
// XOR-swizzled by (m&7) -> bank-minimal MFMA B-frag reads without padding.
__device__ __forceinline__ int xaddr(int m, int n) {
    int c = n >> 3;
    return m * 256 + (((c ^ (m & 7)) << 3) | (n & 7));
}

// Pack W2..W5 (256x256, row-major [k][n]) into MFMA fragment order:
// [l][ct(16)][ks(8)][lane(64)][j(8)], n = 16*ct + (lane&15), k = 32*ks + 8*(lane>>4) + j.
__global__ void prep_weights(const float* __restrict__ W2, const float* __restrict__ W3,
                             const float* __restrict__ W4, const float* __restrict__ W5,
                             unsigned short* __restrict__ whi, unsigned short* __restrict__ wlo) {
    int tid = blockIdx.x * 256 + threadIdx.x;   // 4*65536 total
    int l = tid >> 16;
    int e = tid & 65535;
    int j = e & 7;
    int lane = (e >> 3) & 63;
    int ks = (e >> 9) & 7;
    int ct = (e >> 12) & 15;
    int n = ct * 16 + (lane & 15);
    int k = ks * 32 + (lane >> 4) * 8 + j;
    const float* W = (l == 0) ? W2 : (l == 1) ? W3 : (l == 2) ? W4 : W5;
    float w = W[k * 256 + n];
    unsigned short hi, lo;
    split_bf(w, hi, lo);
    whi[tid] = hi;
    wlo[tid] = lo;
}

// weight A-frag load: ct = 2*wv + ft (wave owns 32 consecutive features)
#define LOADW(WH, WL, L, KS)                                                   \
    do {                                                                       \
        _Pragma("unroll")                                                      \
        for (int _ft = 0; _ft < 2; ++_ft) {                                    \
            const int _idx = ((((L) * 16) + (2 * wv + _ft)) * 8 + (KS)) * 512  \
                             + lane * 8;                                       \
            WH[_ft] = *(const short8*)(whi + _idx);                            \
            WL[_ft] = *(const short8*)(wlo + _idx);                            \
        }                                                                      \
    } while (0)

__global__ __launch_bounds__(512, 4) void mlp_fused(
    const float* __restrict__ coords,
    const float* __restrict__ W1, const float* __restrict__ b1,
    const float* __restrict__ b2, const float* __restrict__ b3,
    const float* __restrict__ b4, const float* __restrict__ b5,
    const float* __restrict__ W6, const float* __restrict__ b6,
    const unsigned short* __restrict__ whi, const unsigned short* __restrict__ wlo,
    float* __restrict__ out, int N)
{
    __shared__ unsigned short Xhi[MT * 256];   // 24 KB
    __shared__ unsigned short Xlo[MT * 256];   // 24 KB  (total 48 KB -> 3 blocks/CU)

    const int tid = threadIdx.x;
    const int m0 = blockIdx.x * MT;

    const int wv   = tid >> 6;     // wave 0..7 owns output features [32*wv, 32*wv+32)
    const int lane = tid & 63;
    const int quad = lane >> 4;
    const int l16  = lane & 15;

    // issue first weight loads NOW -- L2 latency hides under layer 1 + barrier
    short8 cwh[2], cwl[2];
    LOADW(cwh, cwl, 0, 0);

    // ---- layer 1: 2 -> 256 (VALU) -> X. Thread owns 4 cols, 6 rounds. ----
    {
        const int nq = lane * 4;
        const float4v w0 = *(const float4v*)(W1 + nq);          // W1[0][nq..nq+3]
        const float4v w1 = *(const float4v*)(W1 + WIDTH + nq);  // W1[1][nq..nq+3]
        const float4v bb = *(const float4v*)(b1 + nq);
        #pragma unroll
        for (int i = 0; i < MT / 8; ++i) {
            const int m = 8 * i + wv;
            int mg = m0 + m;                  // clamp tail block (dup data, finite)
            if (mg >= N) mg = N - 1;
            const float c0 = coords[mg * 2];  // wave-uniform address
            const float c1 = coords[mg * 2 + 1];
            float v[4];
            #pragma unroll
            for (int j = 0; j < 4; ++j)
                v[j] = fmaxf(fmaf(c0, w0[j], fmaf(c1, w1[j], bb[j])), 0.0f);
            const int a = xaddr(m, nq);       // nq&7 in {0,4}: stays in chunk
            *(uint2v*)(Xhi + a) = (uint2v){phi2(v[0], v[1]), phi2(v[2], v[3])};
            *(uint2v*)(Xlo + a) = (uint2v){plo2(v[0], v[1]), plo2(v[2], v[3])};
        }
    }
    __syncthreads();

    float sdot[3] = {0.f, 0.f, 0.f};   // fused layer-6 partials

    // ---- layers 2..5: 256 -> 256 via 16x16x32 bf16 MFMA, operand-swapped.
    //      Single X buffer: barrier after reads, barrier after writes. ----
    #pragma unroll
    for (int l = 0; l < 4; ++l) {
        const float* bias = (l == 0) ? b2 : (l == 1) ? b3 : (l == 2) ? b4 : b5;

        float4v acc[2][3];   // acc[ft][pt] -- 24 VGPRs
        #pragma unroll
        for (int ft = 0; ft < 2; ++ft)
            #pragma unroll
            for (int pt = 0; pt < 3; ++pt)
                acc[ft][pt] = (float4v){0.f, 0.f, 0.f, 0.f};

        #pragma unroll
        for (int ks = 0; ks < 8; ++ks) {
            // prefetch next weights (next ks, or next layer's ks=0)
            short8 nwh[2], nwl[2];
            if (ks < 7) {
                LOADW(nwh, nwl, l, ks + 1);
            } else if (l < 3) {
                LOADW(nwh, nwl, l + 1, 0);
            }
            // B-frags just-in-time from LDS: B[k][p], p = l16, k = 32*ks+8*quad+j
            short8 xh[3], xl[3];
            #pragma unroll
            for (int pt = 0; pt < 3; ++pt) {
                const int off = xaddr(16 * pt + l16, 32 * ks + 8 * quad);
                xh[pt] = *(const short8*)(Xhi + off);
                xl[pt] = *(const short8*)(Xlo + off);
            }
            __builtin_amdgcn_s_setprio(1);
            // product-major: dependent same-acc MFMAs 6 issue slots apart
            #pragma unroll
            for (int ft = 0; ft < 2; ++ft)
                #pragma unroll
                for (int pt = 0; pt < 3; ++pt)
                    acc[ft][pt] = __builtin_amdgcn_mfma_f32_16x16x32_bf16(cwh[ft], xh[pt], acc[ft][pt], 0, 0, 0);
            #pragma unroll
            for (int ft = 0; ft < 2; ++ft)
                #pragma unroll
                for (int pt = 0; pt < 3; ++pt)
                    acc[ft][pt] = __builtin_amdgcn_mfma_f32_16x16x32_bf16(cwh[ft], xl[pt], acc[ft][pt], 0, 0, 0);
            #pragma unroll
            for (int ft = 0; ft < 2; ++ft)
                #pragma unroll
                for (int pt = 0; pt < 3; ++pt)
                    acc[ft][pt] = __builtin_amdgcn_mfma_f32_16x16x32_bf16(cwl[ft], xh[pt], acc[ft][pt], 0, 0, 0);
            __builtin_amdgcn_s_setprio(0);
            // rotate (SSA renames under full unroll -- no real moves)
            cwh[0] = nwh[0]; cwh[1] = nwh[1];
            cwl[0] = nwl[0]; cwl[1] = nwl[1];
        }
        __syncthreads();   // all waves done READING X before overwrite

        if (l < 3) {
            // epilogue: D row = 4*quad + r (4 consecutive features), col = point.
            // bias+ReLU+perm-pack, b64 writes back into X.
            #pragma unroll
            for (int ft = 0; ft < 2; ++ft) {
                const int nb = 32 * wv + 16 * ft + 4 * quad;   // nb&7 in {0,4}
                const float4v bb = *(const float4v*)(bias + nb);
                #pragma unroll
                for (int pt = 0; pt < 3; ++pt) {
                    const int m = 16 * pt + l16;
                    float v[4];
                    #pragma unroll
                    for (int r = 0; r < 4; ++r)
                        v[r] = fmaxf(acc[ft][pt][r] + bb[r], 0.0f);
                    const int a = xaddr(m, nb);
                    *(uint2v*)(Xhi + a) = (uint2v){phi2(v[0], v[1]), phi2(v[2], v[3])};
                    *(uint2v*)(Xlo + a) = (uint2v){plo2(v[0], v[1]), plo2(v[2], v[3])};
                }
            }
            __syncthreads();   // writes visible before next layer's reads
        } else {
            // fused layer 6: bias5 + ReLU + dot W6 straight from acc (full f32)
            #pragma unroll
            for (int ft = 0; ft < 2; ++ft) {
                const int nb = 32 * wv + 16 * ft + 4 * quad;
                const float4v bb = *(const float4v*)(bias + nb);   // b5
                const float4v w6 = *(const float4v*)(W6 + nb);
                #pragma unroll
                for (int pt = 0; pt < 3; ++pt)
                    #pragma unroll
                    for (int r = 0; r < 4; ++r) {
                        const float v = fmaxf(acc[ft][pt][r] + bb[r], 0.0f);
                        sdot[pt] = fmaf(v, w6[r], sdot[pt]);
                    }
            }
        }
    }

    // ---- layer-6 reduction: quad-shuffle, then cross-wave via LDS ----
    // (post-ks-loop barrier above guarantees all waves are done reading X)
    {
        float* part = (float*)Xhi;
        #pragma unroll
        for (int pt = 0; pt < 3; ++pt) {
            float s = sdot[pt];
            s += __shfl_xor(s, 16);
            s += __shfl_xor(s, 32);
            if (lane < 16) part[wv * 64 + pt * 16 + l16] = s;
        }
        __syncthreads();
        if (tid < MT && m0 + tid < N) {
            float s = b6[0];
            #pragma unroll
            for (int w = 0; w < 8; ++w)
                s += part[w * 64 + tid];
            out[m0 + tid] = s;
        }
    }
}

extern "C" void kernel_launch(void* const* d_in, const int* in_sizes, int n_in,
                              void* d_out, int out_size, void* d_ws, size_t ws_size,
                              hipStream_t stream) {
    const float* coords = (const float*)d_in[0];
    const float* W1 = (const float*)d_in[1];
    const float* b1 = (const float*)d_in[2];
    const float* W2 = (const float*)d_in[3];
    const float* b2 = (const float*)d_in[4];
    const float* W3 = (const float*)d_in[5];
    const float* b3 = (const float*)d_in[6];
    const float* W4 = (const float*)d_in[7];
    const float* b4 = (const float*)d_in[8];
    const float* W5 = (const float*)d_in[9];
    const float* b5 = (const float*)d_in[10];
    const float* W6 = (const float*)d_in[11];
    const float* b6 = (const float*)d_in[12];
    float* out = (float*)d_out;

    unsigned short* whi = (unsigned short*)d_ws;        // 4*65536 ushorts = 512 KB
    unsigned short* wlo = whi + 4 * 65536;              // 512 KB (ws total 1 MB)

    prep_weights<<<1024, 256, 0, stream>>>(W2, W3, W4, W5, whi, wlo);

    const int N = out_size;
    const int nblocks = (N + MT - 1) / MT;              // 524288 / 48 -> 10923
    mlp_fused<<<nblocks, 512, 0, stream>>>(coords, W1, b1, b2, b3, b4, b5,
                                           W6, b6, whi, wlo, out, N);
}

// Round 10
// 687.362 us; speedup vs baseline: 2.0646x; 1.0219x over previous
//
#include <hip/hip_runtime.h>
#include <stdint.h>

// SmallMLP_INR: fused 6-layer MLP (2->256->256x4->1, ReLU) over 524288 points.
// Split-bf16 MFMA (x = hi + lo, truncate split): Y = Xh*Wh + Xh*Wl + Xl*Wh in fp32.
// Operand-swapped: Yt = Wt * Xt (weights = A-frag from global, acts = B-frag in LDS).
// R10 = R7 structure (MT=64, 512 thr, 2 blocks/CU, weight prefetch, fused L6,
// b64 epilogue, setprio) + 32x32x16 MFMA shape. Floor: 96 MFMA x 33.8 cyc =
// 3245 cyc/wave-layer vs 16x16's 192 x 19.4 = 3725 (-13%). R2's 32x32 failure
// confounds (2 waves/SIMD, no prefetch, dependent back-to-back MFMAs, b16
// scatter epilogue) are all removed in this structure. R2 verified the 32x32
// A-frag and C/D layouts bit-exact (same absmax).
// R8/R9 lessons: launch_bounds(512,4) (NOT 6 -- allocator starvation -> spill);
// usable LDS/CU is ~128 KB, so MT=64 (64 KB) is the occupancy optimum.

#define WIDTH 256
#define MT 64

typedef short short8 __attribute__((ext_vector_type(8)));
typedef float float4v __attribute__((ext_vector_type(4)));
typedef float f32x16 __attribute__((ext_vector_type(16)));
typedef unsigned int uint2v __attribute__((ext_vector_type(2)));

// truncate-split f32 -> bf16 hi + bf16 lo (lo also truncated; total ~16-17 bits)
__device__ __forceinline__ void split_bf(float f, unsigned short &hi, unsigned short &lo) {
    union { float f; uint32_t u; } a; a.f = f;
    hi = (unsigned short)(a.u >> 16);
    union { uint32_t u; float f; } h; h.u = a.u & 0xffff0000u;
    union { float f; uint32_t u; } d; d.f = f - h.f;   // exact (Sterbenz)
    lo = (unsigned short)(d.u >> 16);
}

// pack hi(bf16) of two f32 into one u32 via v_perm_b32: D = {a.b2,a.b3,b.b2,b.b3}
__device__ __forceinline__ uint32_t phi2(float a, float b) {
    return __builtin_amdgcn_perm(__float_as_uint(b), __float_as_uint(a), 0x07060302u);
}
// pack lo(bf16) of two f32: residual after hi-truncation, then perm-pack
__device__ __forceinline__ uint32_t plo2(float a, float b) {
    float da = a - __uint_as_float(__float_as_uint(a) & 0xffff0000u);
    float db = b - __uint_as_float(__float_as_uint(b) & 0xffff0000u);
    return __builtin_amdgcn_perm(__float_as_uint(db), __float_as_uint(da), 0x07060302u);
}

// LDS activation addressing: X[m][n], row stride 256 ushorts, 16B-chunk index
// XOR-swizzled by (m&7) -> bank-minimal MFMA B-frag reads without padding.
__device__ __forceinline__ int xaddr(int m, int n) {
    int c = n >> 3;
    return m * 256 + (((c ^ (m & 7)) << 3) | (n & 7));
}

// Pack W2..W5 (256x256, row-major [k][n]) into 32x32x16 MFMA A-fragment order:
// [l(4)][ft(8)][ks(16)][lane(64)][j(8)],
//   n (feature) = 32*ft + (lane&31),  k = 16*ks + 8*(lane>>5) + j.
// (Layout verified bit-exact in R2: same absmax as the 16x16 path.)
__global__ void prep_weights(const float* __restrict__ W2, const float* __restrict__ W3,
                             const float* __restrict__ W4, const float* __restrict__ W5,
                             unsigned short* __restrict__ whi, unsigned short* __restrict__ wlo) {
    int tid = blockIdx.x * 256 + threadIdx.x;   // 4*65536 total
    int l = tid >> 16;
    int e = tid & 65535;
    int j = e & 7;
    int lane = (e >> 3) & 63;
    int ks = (e >> 9) & 15;
    int ft = (e >> 13) & 7;
    int n = 32 * ft + (lane & 31);
    int k = 16 * ks + 8 * (lane >> 5) + j;
    const float* W = (l == 0) ? W2 : (l == 1) ? W3 : (l == 2) ? W4 : W5;
    float w = W[k * 256 + n];
    unsigned short hi, lo;
    split_bf(w, hi, lo);
    whi[tid] = hi;
    wlo[tid] = lo;
}

// weight A-frag load: wave wv owns feature tile ft = wv (32 features)
#define LOADW(WH, WL, L, KS)                                                   \
    do {                                                                       \
        const int _idx = (((L) * 8 + wv) * 16 + (KS)) * 512 + lane * 8;        \
        WH = *(const short8*)(whi + _idx);                                     \
        WL = *(const short8*)(wlo + _idx);                                     \
    } while (0)

__global__ __launch_bounds__(512, 4) void mlp_fused(
    const float* __restrict__ coords,
    const float* __restrict__ W1, const float* __restrict__ b1,
    const float* __restrict__ b2, const float* __restrict__ b3,
    const float* __restrict__ b4, const float* __restrict__ b5,
    const float* __restrict__ W6, const float* __restrict__ b6,
    const unsigned short* __restrict__ whi, const unsigned short* __restrict__ wlo,
    float* __restrict__ out)
{
    __shared__ unsigned short Xhi[MT * 256];   // 32 KB
    __shared__ unsigned short Xlo[MT * 256];   // 32 KB  (total 64 KB -> 2 blocks/CU)

    const int tid = threadIdx.x;
    const int m0 = blockIdx.x * MT;

    const int wv   = tid >> 6;     // wave 0..7 owns output features [32*wv, 32*wv+32)
    const int lane = tid & 63;
    const int half = lane >> 5;    // k-half for A/B frags; feature nibble for C/D
    const int l32  = lane & 31;

    // issue first weight loads NOW -- L2 latency hides under layer 1 + barrier
    short8 cwh, cwl;
    LOADW(cwh, cwl, 0, 0);

    // ---- layer 1: 2 -> 256 (VALU) -> X. Thread owns 4 cols, 8 rounds. ----
    {
        const int nq = lane * 4;
        const float4v w0 = *(const float4v*)(W1 + nq);          // W1[0][nq..nq+3]
        const float4v w1 = *(const float4v*)(W1 + WIDTH + nq);  // W1[1][nq..nq+3]
        const float4v bb = *(const float4v*)(b1 + nq);
        #pragma unroll
        for (int i = 0; i < 8; ++i) {
            const int m = 8 * i + wv;
            const float c0 = coords[(m0 + m) * 2];       // wave-uniform address
            const float c1 = coords[(m0 + m) * 2 + 1];
            float v[4];
            #pragma unroll
            for (int j = 0; j < 4; ++j)
                v[j] = fmaxf(fmaf(c0, w0[j], fmaf(c1, w1[j], bb[j])), 0.0f);
            const int a = xaddr(m, nq);                  // nq&7 in {0,4}: stays in chunk
            *(uint2v*)(Xhi + a) = (uint2v){phi2(v[0], v[1]), phi2(v[2], v[3])};
            *(uint2v*)(Xlo + a) = (uint2v){plo2(v[0], v[1]), plo2(v[2], v[3])};
        }
    }
    __syncthreads();

    float sdot[2] = {0.f, 0.f};   // fused layer-6 partials (pt = 0,1)

    // ---- layers 2..5: 256 -> 256 via 32x32x16 bf16 MFMA, operand-swapped.
    //      Single X buffer: barrier after reads, barrier after writes. ----
    #pragma unroll
    for (int l = 0; l < 4; ++l) {
        const float* bias = (l == 0) ? b2 : (l == 1) ? b3 : (l == 2) ? b4 : b5;

        f32x16 acc[2];   // acc[pt] -- 32 VGPRs
        acc[0] = (f32x16)(0.0f);
        acc[1] = (f32x16)(0.0f);

        #pragma unroll
        for (int ks = 0; ks < 16; ++ks) {
            // prefetch next weights (next ks, or next layer's ks=0)
            short8 nwh, nwl;
            if (ks < 15) {
                LOADW(nwh, nwl, l, ks + 1);
            } else if (l < 3) {
                LOADW(nwh, nwl, l + 1, 0);
            }
            // B-frags just-in-time from LDS: B[k][p], p = 32*pt + l32,
            // k = 16*ks + 8*half + j
            short8 xh[2], xl[2];
            #pragma unroll
            for (int pt = 0; pt < 2; ++pt) {
                const int off = xaddr(32 * pt + l32, 16 * ks + 8 * half);
                xh[pt] = *(const short8*)(Xhi + off);
                xl[pt] = *(const short8*)(Xlo + off);
            }
            __builtin_amdgcn_s_setprio(1);
            // product-major: same-acc MFMAs 2 issue slots (~68 pipe-cyc) apart
            #pragma unroll
            for (int pt = 0; pt < 2; ++pt)
                acc[pt] = __builtin_amdgcn_mfma_f32_32x32x16_bf16(cwh, xh[pt], acc[pt], 0, 0, 0);
            #pragma unroll
            for (int pt = 0; pt < 2; ++pt)
                acc[pt] = __builtin_amdgcn_mfma_f32_32x32x16_bf16(cwh, xl[pt], acc[pt], 0, 0, 0);
            #pragma unroll
            for (int pt = 0; pt < 2; ++pt)
                acc[pt] = __builtin_amdgcn_mfma_f32_32x32x16_bf16(cwl, xh[pt], acc[pt], 0, 0, 0);
            __builtin_amdgcn_s_setprio(0);
            // rotate (SSA renames under full unroll -- no real moves)
            cwh = nwh; cwl = nwl;
        }
        __syncthreads();   // all waves done READING X before overwrite

        if (l < 3) {
            // epilogue: C/D row = (reg&3) + 8*(reg>>2) + 4*half = feature offset
            // (reg-quad rg -> 4 CONSECUTIVE features), col = point 32*pt + l32.
            #pragma unroll
            for (int rg = 0; rg < 4; ++rg) {
                const int nb = 32 * wv + 8 * rg + 4 * half;    // nb&7 in {0,4}
                const float4v bb = *(const float4v*)(bias + nb);
                #pragma unroll
                for (int pt = 0; pt < 2; ++pt) {
                    const int m = 32 * pt + l32;
                    float v[4];
                    #pragma unroll
                    for (int r = 0; r < 4; ++r)
                        v[r] = fmaxf(acc[pt][4 * rg + r] + bb[r], 0.0f);
                    const int a = xaddr(m, nb);
                    *(uint2v*)(Xhi + a) = (uint2v){phi2(v[0], v[1]), phi2(v[2], v[3])};
                    *(uint2v*)(Xlo + a) = (uint2v){plo2(v[0], v[1]), plo2(v[2], v[3])};
                }
            }
            __syncthreads();   // writes visible before next layer's reads
        } else {
            // fused layer 6: bias5 + ReLU + dot W6 straight from acc (full f32)
            #pragma unroll
            for (int rg = 0; rg < 4; ++rg) {
                const int nb = 32 * wv + 8 * rg + 4 * half;
                const float4v bb = *(const float4v*)(bias + nb);   // b5
                const float4v w6 = *(const float4v*)(W6 + nb);
                #pragma unroll
                for (int pt = 0; pt < 2; ++pt)
                    #pragma unroll
                    for (int r = 0; r < 4; ++r) {
                        const float v = fmaxf(acc[pt][4 * rg + r] + bb[r], 0.0f);
                        sdot[pt] = fmaf(v, w6[r], sdot[pt]);
                    }
            }
        }
    }

    // ---- layer-6 reduction: fold lane halves, then cross-wave via LDS ----
    // sdot[pt] covers 16 of the wave's 32 features (those with this half);
    // shfl_xor(32) folds the halves -> lanes share full per-wave partials.
    {
        float* part = (float*)Xhi;
        #pragma unroll
        for (int pt = 0; pt < 2; ++pt) {
            float s = sdot[pt];
            s += __shfl_xor(s, 32);
            if (lane < 32) part[wv * 64 + pt * 32 + l32] = s;
        }
        __syncthreads();
        if (tid < 64) {
            float s = b6[0];
            #pragma unroll
            for (int w = 0; w < 8; ++w)
                s += part[w * 64 + tid];
            out[m0 + tid] = s;
        }
    }
}

extern "C" void kernel_launch(void* const* d_in, const int* in_sizes, int n_in,
                              void* d_out, int out_size, void* d_ws, size_t ws_size,
                              hipStream_t stream) {
    const float* coords = (const float*)d_in[0];
    const float* W1 = (const float*)d_in[1];
    const float* b1 = (const float*)d_in[2];
    const float* W2 = (const float*)d_in[3];
    const float* b2 = (const float*)d_in[4];
    const float* W3 = (const float*)d_in[5];
    const float* b3 = (const float*)d_in[6];
    const float* W4 = (const float*)d_in[7];
    const float* b4 = (const float*)d_in[8];
    const float* W5 = (const float*)d_in[9];
    const float* b5 = (const float*)d_in[10];
    const float* W6 = (const float*)d_in[11];
    const float* b6 = (const float*)d_in[12];
    float* out = (float*)d_out;

    unsigned short* whi = (unsigned short*)d_ws;        // 4*65536 ushorts = 512 KB
    unsigned short* wlo = whi + 4 * 65536;              // 512 KB (ws total 1 MB)

    prep_weights<<<1024, 256, 0, stream>>>(W2, W3, W4, W5, whi, wlo);

    const int nblocks = out_size / MT;                  // 524288 / 64 = 8192
    mlp_fused<<<nblocks, 512, 0, stream>>>(coords, W1, b1, b2, b3, b4, b5,
                                           W6, b6, whi, wlo, out);
}